// Round 2
// baseline (364.473 us; speedup 1.0000x reference)
//
#include <hip/hip_runtime.h>

#define B_ 4
#define T_ 2048
#define S_ 2048
#define D_ 256
#define F_ 1024

typedef unsigned short ushort_t;
typedef __bf16 v8bf __attribute__((ext_vector_type(8)));
typedef float v4f __attribute__((ext_vector_type(4)));
typedef __attribute__((address_space(1))) const unsigned int gas_uint;
typedef __attribute__((address_space(3))) unsigned int las_uint;

__device__ __forceinline__ ushort_t f2bf(float f) {
  unsigned u = __float_as_uint(f);
  unsigned r = (u + 0x7FFFu + ((u >> 16) & 1u)) >> 16;   // RTNE
  return (ushort_t)r;
}

// ---------------------------------------------------------------------------
// Weight prep: fp32 [K,N] -> bf16 [N,K] (transpose + convert), 8 matrices.
// ---------------------------------------------------------------------------
struct WP { const float* s; ushort_t* d; int K, N; };
struct WP8 { WP m[8]; };

__global__ void prep_weights_k(WP8 a) {
  WP w = a.m[blockIdx.z];
  int k0 = blockIdx.x * 64, n0 = blockIdx.y * 64;
  if (k0 >= w.K || n0 >= w.N) return;
  __shared__ ushort_t tile[64][65];
  int tx = threadIdx.x, ty = threadIdx.y;
  for (int r = ty; r < 64; r += 4)
    tile[r][tx] = f2bf(w.s[(size_t)(k0 + r) * w.N + n0 + tx]);
  __syncthreads();
  for (int r = ty; r < 64; r += 4)
    w.d[(size_t)(n0 + r) * w.K + k0 + tx] = tile[tx][r];
}

// fp32 -> bf16 elementwise for y and Z (grid.y selects tensor)
__global__ void cvt_k(const float* __restrict__ a, ushort_t* __restrict__ oa,
                      const float* __restrict__ b, ushort_t* __restrict__ ob) {
  int i = blockIdx.x * 256 + threadIdx.x;
  const float* s = blockIdx.y ? b : a;
  ushort_t* d = blockIdx.y ? ob : oa;
  size_t off = (size_t)i * 8;
  float4 v0 = *(const float4*)(s + off);
  float4 v1 = *(const float4*)(s + off + 4);
  union { ushort_t u[8]; uint4 v; } pk;
  pk.u[0] = f2bf(v0.x); pk.u[1] = f2bf(v0.y); pk.u[2] = f2bf(v0.z); pk.u[3] = f2bf(v0.w);
  pk.u[4] = f2bf(v1.x); pk.u[5] = f2bf(v1.y); pk.u[6] = f2bf(v1.z); pk.u[7] = f2bf(v1.w);
  *(uint4*)(d + off) = pk.v;
}

// bf16 [rows,cols] -> bf16 [cols,rows] per batch (grid.z)
__global__ void transpose_bf16_k(const ushort_t* __restrict__ in, ushort_t* __restrict__ out,
                                 int rows, int cols) {
  in  += (size_t)blockIdx.z * rows * cols;
  out += (size_t)blockIdx.z * rows * cols;
  __shared__ ushort_t tile[64][65];
  int r0 = blockIdx.x * 64, c0 = blockIdx.y * 64;
  int tx = threadIdx.x, ty = threadIdx.y;
  for (int r = ty; r < 64; r += 4)
    tile[r][tx] = in[(size_t)(r0 + r) * cols + c0 + tx];
  __syncthreads();
  for (int r = ty; r < 64; r += 4)
    out[(size_t)(c0 + r) * rows + r0 + tx] = tile[tx][r];
}

// ---------------------------------------------------------------------------
// GEMM: C[M,N] = alpha * A[M,K] @ Bt[N,K]^T + bias.  A,Bt bf16; C fp32 and/or
// bf16.  128x64 tile, BK=64, 4 waves (2x2), global_load_lds(16B) with XOR
// swizzle (pre-swizzled source + swizzled ds_read — both sides, rule #21).
// mfma_f32_16x16x32_bf16; C/D layout col=lane&15, row=(lane>>4)*4+i (m89).
// crow0: absolute row offset of A's first row (for causal skip only).
// ---------------------------------------------------------------------------
template<bool RELU>
__global__ __launch_bounds__(256, 2) void gemm_bt(
    const ushort_t* __restrict__ A, int lda, long long sAz,
    const ushort_t* __restrict__ Bt, int ldb, long long sBz,
    const float* __restrict__ bias,
    float* __restrict__ Cf, ushort_t* __restrict__ Cb, int ldc, long long sCz,
    int K, float alpha, int causal, int crow0) {
  const int n0 = blockIdx.x * 64, m0 = blockIdx.y * 128;
  if (causal && n0 > crow0 + m0 + 127) return;   // fully-masked score block: skip
  A  += (long long)blockIdx.z * sAz;
  Bt += (long long)blockIdx.z * sBz;
  const long long coff = (long long)blockIdx.z * sCz;
  const int t = threadIdx.x, lane = t & 63, wv = t >> 6;
  const int wm = wv >> 1, wn = wv & 1;
  const int kslot = lane >> 4, l15 = lane & 15;
  __shared__ __align__(16) char smem[24576];   // A 16KB + B 8KB
  char* sA = smem;
  char* sB = smem + 16384;

  v4f acc[4][2];
  v4f zero = {0.f, 0.f, 0.f, 0.f};
#pragma unroll
  for (int m = 0; m < 4; ++m)
#pragma unroll
    for (int n = 0; n < 2; ++n) acc[m][n] = zero;

  for (int kk = 0; kk < K; kk += 64) {
    __syncthreads();
    // A tile: 128 rows x 64 k (16KB = 1024 granules of 16B), 4 instrs/wave
#pragma unroll
    for (int q = 0; q < 4; ++q) {
      int g = q * 256 + t;
      int row = g >> 3, j = g & 7;
      const ushort_t* src = A + (long long)(m0 + row) * lda + kk + ((j ^ (row & 7)) << 3);
      __builtin_amdgcn_global_load_lds((gas_uint*)src,
          (las_uint*)(sA + q * 4096 + (wv << 10)), 16, 0, 0);
    }
    // B tile: 64 rows x 64 k (8KB)
#pragma unroll
    for (int q = 0; q < 2; ++q) {
      int g = q * 256 + t;
      int row = g >> 3, j = g & 7;
      const ushort_t* src = Bt + (long long)(n0 + row) * ldb + kk + ((j ^ (row & 7)) << 3);
      __builtin_amdgcn_global_load_lds((gas_uint*)src,
          (las_uint*)(sB + q * 4096 + (wv << 10)), 16, 0, 0);
    }
    __syncthreads();
#pragma unroll
    for (int ks = 0; ks < 2; ++ks) {
      v8bf af[4]; v8bf bfr[2];
#pragma unroll
      for (int m = 0; m < 4; ++m) {
        int row = wm * 64 + m * 16 + l15;
        int gs = (ks * 4 + kslot) ^ (row & 7);
        af[m] = *(const v8bf*)(sA + ((row * 8 + gs) << 4));
      }
#pragma unroll
      for (int n = 0; n < 2; ++n) {
        int row = wn * 32 + n * 16 + l15;
        int gs = (ks * 4 + kslot) ^ (row & 7);
        bfr[n] = *(const v8bf*)(sB + ((row * 8 + gs) << 4));
      }
#pragma unroll
      for (int m = 0; m < 4; ++m)
#pragma unroll
        for (int n = 0; n < 2; ++n)
          acc[m][n] = __builtin_amdgcn_mfma_f32_16x16x32_bf16(af[m], bfr[n], acc[m][n], 0, 0, 0);
    }
  }
#pragma unroll
  for (int m = 0; m < 4; ++m) {
    int grow0 = m0 + wm * 64 + m * 16 + (kslot << 2);
#pragma unroll
    for (int n = 0; n < 2; ++n) {
      int gcol = n0 + wn * 32 + n * 16 + l15;
      float bb = bias ? bias[gcol] : 0.f;
#pragma unroll
      for (int i = 0; i < 4; ++i) {
        float v = acc[m][n][i] * alpha + bb;
        if (RELU) v = fmaxf(v, 0.f);
        long long off = coff + (long long)(grow0 + i) * ldc + gcol;
        if (Cf) Cf[off] = v;
        if (Cb) Cb[off] = f2bf(v);
      }
    }
  }
}

// ---------------------------------------------------------------------------
// Row softmax over S=2048 fp32 scores; writes bf16 probs IN-PLACE over the
// first half of each row's own fp32 storage (PV GEMM reads lda=2*S bf16).
// crow0: absolute row offset (causal valid length = crow0 + row + 1).
// ---------------------------------------------------------------------------
__global__ __launch_bounds__(256) void softmax_k(float* scores, int causal, int crow0) {
  int row = blockIdx.x;
  float* rp = scores + ((size_t)blockIdx.y * T_ + row) * S_;
  int t = threadIdx.x;
  int valid = causal ? crow0 + row + 1 : S_;
  float x[8];
  float4 v0 = *(const float4*)(rp + t * 8);
  float4 v1 = *(const float4*)(rp + t * 8 + 4);
  x[0] = v0.x; x[1] = v0.y; x[2] = v0.z; x[3] = v0.w;
  x[4] = v1.x; x[5] = v1.y; x[6] = v1.z; x[7] = v1.w;
  float m = -3.0e38f;
#pragma unroll
  for (int j = 0; j < 8; ++j) if (t * 8 + j < valid) m = fmaxf(m, x[j]);
  for (int mk = 1; mk < 64; mk <<= 1) m = fmaxf(m, __shfl_xor(m, mk));
  __shared__ float rbuf[8];
  if ((t & 63) == 0) rbuf[t >> 6] = m;
  __syncthreads();
  m = fmaxf(fmaxf(rbuf[0], rbuf[1]), fmaxf(rbuf[2], rbuf[3]));
  float p[8]; float l = 0.f;
#pragma unroll
  for (int j = 0; j < 8; ++j) { p[j] = (t * 8 + j < valid) ? __expf(x[j] - m) : 0.f; l += p[j]; }
  for (int mk = 1; mk < 64; mk <<= 1) l += __shfl_xor(l, mk);
  if ((t & 63) == 0) rbuf[4 + (t >> 6)] = l;
  __syncthreads();
  l = rbuf[4] + rbuf[5] + rbuf[6] + rbuf[7];
  float inv = 1.f / l;
  union { ushort_t u[8]; uint4 v; } pk;
#pragma unroll
  for (int j = 0; j < 8; ++j) pk.u[j] = f2bf(p[j] * inv);
  __syncthreads();   // all row reads complete before aliasing writes
  *(uint4*)((ushort_t*)rp + t * 8) = pk.v;
}

// ---------------------------------------------------------------------------
// out = LN(base + delta) * g + be; writes fp32 (residual) and optional bf16.
// One wave per 256-elem row; 4 rows per block.
// ---------------------------------------------------------------------------
__global__ __launch_bounds__(256) void add_ln_k(
    const float* __restrict__ base, const float* __restrict__ delta,
    const float* __restrict__ g, const float* __restrict__ be,
    float* __restrict__ outf, ushort_t* __restrict__ outb) {
  int row = blockIdx.x * 4 + (threadIdx.x >> 6);
  int lane = threadIdx.x & 63;
  size_t off = (size_t)row * 256 + lane * 4;
  float4 xv = *(const float4*)(base + off);
  float4 dv = *(const float4*)(delta + off);
  float s0 = xv.x + dv.x, s1 = xv.y + dv.y, s2 = xv.z + dv.z, s3 = xv.w + dv.w;
  float sum = s0 + s1 + s2 + s3;
  for (int mk = 1; mk < 64; mk <<= 1) sum += __shfl_xor(sum, mk);
  float mean = sum * (1.f / 256.f);
  float e0 = s0 - mean, e1 = s1 - mean, e2 = s2 - mean, e3 = s3 - mean;
  float ss = e0 * e0 + e1 * e1 + e2 * e2 + e3 * e3;
  for (int mk = 1; mk < 64; mk <<= 1) ss += __shfl_xor(ss, mk);
  float rstd = rsqrtf(ss * (1.f / 256.f) + 1e-5f);
  float4 gv = *(const float4*)(g + lane * 4);
  float4 bv = *(const float4*)(be + lane * 4);
  float o0 = e0 * rstd * gv.x + bv.x, o1 = e1 * rstd * gv.y + bv.y;
  float o2 = e2 * rstd * gv.z + bv.z, o3 = e3 * rstd * gv.w + bv.w;
  float4 ov; ov.x = o0; ov.y = o1; ov.z = o2; ov.w = o3;
  *(float4*)(outf + off) = ov;
  if (outb) {
    union { ushort_t u[4]; uint2 v; } pk;
    pk.u[0] = f2bf(o0); pk.u[1] = f2bf(o1); pk.u[2] = f2bf(o2); pk.u[3] = f2bf(o3);
    *(uint2*)(outb + off) = pk.v;
  }
}

// ---------------------------------------------------------------------------
extern "C" void kernel_launch(void* const* d_in, const int* in_sizes, int n_in,
                              void* d_out, int out_size, void* d_ws, size_t ws_size,
                              hipStream_t stream) {
  const float* y   = (const float*)d_in[0];
  const float* Z   = (const float*)d_in[1];
  const float* Wq1 = (const float*)d_in[3];  const float* bq1 = (const float*)d_in[4];
  const float* Wk1 = (const float*)d_in[5];  const float* bk1 = (const float*)d_in[6];
  const float* Wv1 = (const float*)d_in[7];  const float* bv1 = (const float*)d_in[8];
  const float* Wq2 = (const float*)d_in[9];  const float* bq2 = (const float*)d_in[10];
  const float* Wk2 = (const float*)d_in[11]; const float* bk2 = (const float*)d_in[12];
  const float* Wv2 = (const float*)d_in[13]; const float* bv2 = (const float*)d_in[14];
  const float* W1  = (const float*)d_in[15]; const float* b1  = (const float*)d_in[16];
  const float* W2  = (const float*)d_in[17]; const float* b2  = (const float*)d_in[18];
  const float* g1  = (const float*)d_in[19]; const float* be1 = (const float*)d_in[20];
  const float* g2  = (const float*)d_in[21]; const float* be2 = (const float*)d_in[22];
  const float* g3  = (const float*)d_in[23]; const float* be3 = (const float*)d_in[24];
  float* out = (float*)d_out;

  char* p = (char*)d_ws;
  auto alloc = [&](size_t sz) { char* r = p; p += (sz + 255) & ~(size_t)255; return r; };
  const size_t NBT = (size_t)B_ * T_ * D_;   // 2,097,152 elems
  ushort_t* Wq1t = (ushort_t*)alloc(D_ * D_ * 2);
  ushort_t* Wk1t = (ushort_t*)alloc(D_ * D_ * 2);
  ushort_t* Wv1t = (ushort_t*)alloc(D_ * D_ * 2);
  ushort_t* Wq2t = (ushort_t*)alloc(D_ * D_ * 2);
  ushort_t* Wk2t = (ushort_t*)alloc(D_ * D_ * 2);
  ushort_t* Wv2t = (ushort_t*)alloc(D_ * D_ * 2);
  ushort_t* W1t  = (ushort_t*)alloc((size_t)F_ * D_ * 2);
  ushort_t* W2t  = (ushort_t*)alloc((size_t)D_ * F_ * 2);
  ushort_t* yb  = (ushort_t*)alloc(NBT * 2);
  ushort_t* Zb  = (ushort_t*)alloc(NBT * 2);
  float*    y1f = (float*)alloc(NBT * 4);
  ushort_t* y1b = (ushort_t*)alloc(NBT * 2);
  float*    y2f = (float*)alloc(NBT * 4);
  ushort_t* y2b = (ushort_t*)alloc(NBT * 2);
  ushort_t* Qb = (ushort_t*)alloc(NBT * 2);   // Qb..Vt contiguous (4x4MB);
  ushort_t* Kb = (ushort_t*)alloc(NBT * 2);   // Hb (16MB) aliases them in FFN
  ushort_t* Vb = (ushort_t*)alloc(NBT * 2);
  ushort_t* Vt = (ushort_t*)alloc(NBT * 2);
  ushort_t* Hb = Qb;
  float* tmp = (float*)alloc(NBT * 4);
  float* scores = (float*)p;
  size_t remain = (ws_size > (size_t)(p - (char*)d_ws))
                      ? ws_size - (size_t)(p - (char*)d_ws) : 0;
  const size_t rowb = (size_t)S_ * 4;            // bytes per score row
  // Score-buffer policy: full batch (CH=4) > per-batch (CH=1) > T-chunks.
  int CH = 0, TC = 0;
  if (remain >= (size_t)B_ * T_ * rowb)      { CH = B_; TC = T_; }
  else if (remain >= (size_t)T_ * rowb)      { CH = 1;  TC = T_; }
  else {
    int tc = (int)(remain / (rowb * 128)) * 128;   // multiple of 128 rows
    if (tc > T_) tc = T_;
    CH = 1; TC = tc;                                // TC==0 -> ws too small; nothing we can do
  }

  // --- prep ---
  WP8 wp;
  wp.m[0] = {Wq1, Wq1t, D_, D_}; wp.m[1] = {Wk1, Wk1t, D_, D_};
  wp.m[2] = {Wv1, Wv1t, D_, D_}; wp.m[3] = {Wq2, Wq2t, D_, D_};
  wp.m[4] = {Wk2, Wk2t, D_, D_}; wp.m[5] = {Wv2, Wv2t, D_, D_};
  wp.m[6] = {W1, W1t, D_, F_};   wp.m[7] = {W2, W2t, F_, D_};
  prep_weights_k<<<dim3(16, 16, 8), dim3(64, 4), 0, stream>>>(wp);
  cvt_k<<<dim3((int)(NBT / 8 / 256), 2), 256, 0, stream>>>(y, yb, Z, Zb);

  auto gemm = [&](const ushort_t* A, int lda, long long sAz,
                  const ushort_t* Bt, int ldb, long long sBz,
                  const float* bias, float* Cf, ushort_t* Cb, int ldc, long long sCz,
                  int M, int N, int K, float alpha, int causal, bool relu, int Zn, int crow0) {
    dim3 g(N / 64, M / 128, Zn);
    if (relu)
      gemm_bt<true><<<g, 256, 0, stream>>>(A, lda, sAz, Bt, ldb, sBz, bias, Cf, Cb, ldc, sCz, K, alpha, causal, crow0);
    else
      gemm_bt<false><<<g, 256, 0, stream>>>(A, lda, sAz, Bt, ldb, sBz, bias, Cf, Cb, ldc, sCz, K, alpha, causal, crow0);
  };

  auto attention = [&](const ushort_t* Q, const ushort_t* Kc, const ushort_t* Vc,
                       float* attout, int causal) {
    transpose_bf16_k<<<dim3(S_ / 64, D_ / 64, B_), dim3(64, 4), 0, stream>>>(Vc, Vt, S_, D_);
    if (TC <= 0) return;
    for (int b0 = 0; b0 < B_; b0 += CH) {
      for (int t0 = 0; t0 < T_; t0 += TC) {
        int rows = (t0 + TC <= T_) ? TC : (T_ - t0);
        gemm(Q + ((size_t)b0 * T_ + t0) * D_, D_, (long long)T_ * D_,
             Kc + (size_t)b0 * S_ * D_, D_, (long long)S_ * D_,
             nullptr, scores, nullptr, S_, (long long)T_ * S_,
             rows, S_, D_, 0.0625f, causal, false, CH, t0);
        softmax_k<<<dim3(rows, CH), 256, 0, stream>>>(scores, causal, t0);
        gemm((const ushort_t*)scores, 2 * S_, (long long)T_ * 2 * S_,
             Vt + (size_t)b0 * D_ * S_, S_, (long long)D_ * S_,
             nullptr, attout + ((size_t)b0 * T_ + t0) * D_, nullptr, D_, (long long)T_ * D_,
             rows, D_, S_, 1.f, 0, false, CH, 0);
      }
    }
  };

  // --- self-attention ---
  gemm(yb, D_, 0, Wq1t, D_, 0, bq1, nullptr, Qb, D_, 0, B_ * T_, D_, D_, 1.f, 0, false, 1, 0);
  gemm(yb, D_, 0, Wk1t, D_, 0, bk1, nullptr, Kb, D_, 0, B_ * T_, D_, D_, 1.f, 0, false, 1, 0);
  gemm(yb, D_, 0, Wv1t, D_, 0, bv1, nullptr, Vb, D_, 0, B_ * T_, D_, D_, 1.f, 0, false, 1, 0);
  attention(Qb, Kb, Vb, tmp, 1);
  add_ln_k<<<dim3(B_ * T_ / 4), 256, 0, stream>>>(y, tmp, g1, be1, y1f, y1b);

  // --- cross-attention ---
  gemm(y1b, D_, 0, Wq2t, D_, 0, bq2, nullptr, Qb, D_, 0, B_ * T_, D_, D_, 1.f, 0, false, 1, 0);
  gemm(Zb,  D_, 0, Wk2t, D_, 0, bk2, nullptr, Kb, D_, 0, B_ * S_, D_, D_, 1.f, 0, false, 1, 0);
  gemm(Zb,  D_, 0, Wv2t, D_, 0, bv2, nullptr, Vb, D_, 0, B_ * S_, D_, D_, 1.f, 0, false, 1, 0);
  attention(Qb, Kb, Vb, tmp, 0);
  add_ln_k<<<dim3(B_ * T_ / 4), 256, 0, stream>>>(y1f, tmp, g2, be2, y2f, y2b);

  // --- FFN ---
  gemm(y2b, D_, 0, W1t, D_, 0, b1, nullptr, Hb, F_, 0, B_ * T_, F_, D_, 1.f, 0, true, 1, 0);
  gemm(Hb, F_, 0, W2t, F_, 0, b2, tmp, nullptr, D_, 0, B_ * T_, D_, F_, 1.f, 0, false, 1, 0);
  add_ln_k<<<dim3(B_ * T_ / 4), 256, 0, stream>>>(y2f, tmp, g3, be3, out, nullptr);
}

// Round 3
// 336.387 us; speedup vs baseline: 1.0835x; 1.0835x over previous
//
#include <hip/hip_runtime.h>

#define B_ 4
#define T_ 2048
#define S_ 2048
#define D_ 256
#define F_ 1024

typedef unsigned short ushort_t;
typedef __bf16 v8bf __attribute__((ext_vector_type(8)));
typedef float v4f __attribute__((ext_vector_type(4)));
typedef __attribute__((address_space(1))) const unsigned int gas_uint;
typedef __attribute__((address_space(3))) unsigned int las_uint;

__device__ __forceinline__ ushort_t f2bf(float f) {
  unsigned u = __float_as_uint(f);
  unsigned r = (u + 0x7FFFu + ((u >> 16) & 1u)) >> 16;   // RTNE
  return (ushort_t)r;
}
__device__ __forceinline__ float bf2f(ushort_t u) {
  return __uint_as_float((unsigned)u << 16);
}

// ---------------------------------------------------------------------------
// Weight prep: fp32 [K,N] -> bf16 [N,K] (transpose + convert), 8 matrices.
// ---------------------------------------------------------------------------
struct WP { const float* s; ushort_t* d; int K, N; };
struct WP8 { WP m[8]; };

__global__ void prep_weights_k(WP8 a) {
  WP w = a.m[blockIdx.z];
  int k0 = blockIdx.x * 64, n0 = blockIdx.y * 64;
  if (k0 >= w.K || n0 >= w.N) return;
  __shared__ ushort_t tile[64][65];
  int tx = threadIdx.x, ty = threadIdx.y;
  for (int r = ty; r < 64; r += 4)
    tile[r][tx] = f2bf(w.s[(size_t)(k0 + r) * w.N + n0 + tx]);
  __syncthreads();
  for (int r = ty; r < 64; r += 4)
    w.d[(size_t)(n0 + r) * w.K + k0 + tx] = tile[tx][r];
}

// pack biases: bqkv1 = [bq1|bk1|bv1] (768), bkv2 = [bk2|bv2] (512)
__global__ void pack_bias_k(const float* bq1, const float* bk1, const float* bv1,
                            const float* bk2, const float* bv2,
                            float* bqkv1, float* bkv2) {
  int t = blockIdx.x * 256 + threadIdx.x;
  if (t < 768) bqkv1[t] = (t < 256) ? bq1[t] : (t < 512) ? bk1[t - 256] : bv1[t - 512];
  if (t < 512) bkv2[t] = (t < 256) ? bk2[t] : bv2[t - 256];
}

// fp32 -> bf16 elementwise for y and Z (grid.y selects tensor)
__global__ void cvt_k(const float* __restrict__ a, ushort_t* __restrict__ oa,
                      const float* __restrict__ b, ushort_t* __restrict__ ob) {
  int i = blockIdx.x * 256 + threadIdx.x;
  const float* s = blockIdx.y ? b : a;
  ushort_t* d = blockIdx.y ? ob : oa;
  size_t off = (size_t)i * 8;
  float4 v0 = *(const float4*)(s + off);
  float4 v1 = *(const float4*)(s + off + 4);
  union { ushort_t u[8]; uint4 v; } pk;
  pk.u[0] = f2bf(v0.x); pk.u[1] = f2bf(v0.y); pk.u[2] = f2bf(v0.z); pk.u[3] = f2bf(v0.w);
  pk.u[4] = f2bf(v1.x); pk.u[5] = f2bf(v1.y); pk.u[6] = f2bf(v1.z); pk.u[7] = f2bf(v1.w);
  *(uint4*)(d + off) = pk.v;
}

// bf16 [rows,cols] (row stride ldin, batch stride sIz) -> bf16 [cols,rows]
__global__ void transpose_bf16_k(const ushort_t* __restrict__ in, long long sIz, int ldin,
                                 ushort_t* __restrict__ out, long long sOz,
                                 int rows, int cols) {
  in  += (size_t)blockIdx.z * sIz;
  out += (size_t)blockIdx.z * sOz;
  __shared__ ushort_t tile[64][65];
  int r0 = blockIdx.x * 64, c0 = blockIdx.y * 64;
  int tx = threadIdx.x, ty = threadIdx.y;
  for (int r = ty; r < 64; r += 4)
    tile[r][tx] = in[(size_t)(r0 + r) * ldin + c0 + tx];
  __syncthreads();
  for (int r = ty; r < 64; r += 4)
    out[(size_t)(c0 + r) * rows + r0 + tx] = tile[tx][r];
}

// ---------------------------------------------------------------------------
// GEMM: C[M,N] = alpha * A[M,K] @ Bt[N,K]^T + bias.  A,Bt bf16; C fp32 and/or
// bf16.  128x64 tile, BK=64, 4 waves (2x2), global_load_lds(16B) with XOR
// swizzle (pre-swizzled source + swizzled ds_read — both sides, rule #21).
// mfma_f32_16x16x32_bf16; C/D layout col=lane&15, row=(lane>>4)*4+i (m89).
// causal: skip blocks fully above diagonal (score GEMM).
// kcausal: limit K-loop to crow0+m0+128 (PV GEMM, probs zero beyond).
// ---------------------------------------------------------------------------
template<bool RELU>
__global__ __launch_bounds__(256, 2) void gemm_bt(
    const ushort_t* __restrict__ A, int lda, long long sAz,
    const ushort_t* __restrict__ Bt, int ldb, long long sBz,
    const float* __restrict__ bias,
    float* __restrict__ Cf, ushort_t* __restrict__ Cb, int ldc, long long sCz,
    int K, float alpha, int causal, int kcausal, int crow0) {
  const int n0 = blockIdx.x * 64, m0 = blockIdx.y * 128;
  if (causal && n0 > crow0 + m0 + 127) return;   // fully-masked score block
  const int Keff = kcausal ? ((crow0 + m0 + 128 < K) ? crow0 + m0 + 128 : K) : K;
  A  += (long long)blockIdx.z * sAz;
  Bt += (long long)blockIdx.z * sBz;
  const long long coff = (long long)blockIdx.z * sCz;
  const int t = threadIdx.x, lane = t & 63, wv = t >> 6;
  const int wm = wv >> 1, wn = wv & 1;
  const int kslot = lane >> 4, l15 = lane & 15;
  __shared__ __align__(16) char smem[24576];   // A 16KB + B 8KB
  char* sA = smem;
  char* sB = smem + 16384;

  v4f acc[4][2];
  v4f zero = {0.f, 0.f, 0.f, 0.f};
#pragma unroll
  for (int m = 0; m < 4; ++m)
#pragma unroll
    for (int n = 0; n < 2; ++n) acc[m][n] = zero;

  for (int kk = 0; kk < Keff; kk += 64) {
    __syncthreads();
    // A tile: 128 rows x 64 k (16KB), 4 load_lds/wave
#pragma unroll
    for (int q = 0; q < 4; ++q) {
      int g = q * 256 + t;
      int row = g >> 3, j = g & 7;
      const ushort_t* src = A + (long long)(m0 + row) * lda + kk + ((j ^ (row & 7)) << 3);
      __builtin_amdgcn_global_load_lds((gas_uint*)src,
          (las_uint*)(sA + q * 4096 + (wv << 10)), 16, 0, 0);
    }
    // B tile: 64 rows x 64 k (8KB)
#pragma unroll
    for (int q = 0; q < 2; ++q) {
      int g = q * 256 + t;
      int row = g >> 3, j = g & 7;
      const ushort_t* src = Bt + (long long)(n0 + row) * ldb + kk + ((j ^ (row & 7)) << 3);
      __builtin_amdgcn_global_load_lds((gas_uint*)src,
          (las_uint*)(sB + q * 4096 + (wv << 10)), 16, 0, 0);
    }
    __syncthreads();
#pragma unroll
    for (int ks = 0; ks < 2; ++ks) {
      v8bf af[4]; v8bf bfr[2];
#pragma unroll
      for (int m = 0; m < 4; ++m) {
        int row = wm * 64 + m * 16 + l15;
        int gs = (ks * 4 + kslot) ^ (row & 7);
        af[m] = *(const v8bf*)(sA + ((row * 8 + gs) << 4));
      }
#pragma unroll
      for (int n = 0; n < 2; ++n) {
        int row = wn * 32 + n * 16 + l15;
        int gs = (ks * 4 + kslot) ^ (row & 7);
        bfr[n] = *(const v8bf*)(sB + ((row * 8 + gs) << 4));
      }
#pragma unroll
      for (int m = 0; m < 4; ++m)
#pragma unroll
        for (int n = 0; n < 2; ++n)
          acc[m][n] = __builtin_amdgcn_mfma_f32_16x16x32_bf16(af[m], bfr[n], acc[m][n], 0, 0, 0);
    }
  }
#pragma unroll
  for (int m = 0; m < 4; ++m) {
    int grow0 = m0 + wm * 64 + m * 16 + (kslot << 2);
#pragma unroll
    for (int n = 0; n < 2; ++n) {
      int gcol = n0 + wn * 32 + n * 16 + l15;
      float bb = bias ? bias[gcol] : 0.f;
#pragma unroll
      for (int i = 0; i < 4; ++i) {
        float v = acc[m][n][i] * alpha + bb;
        if (RELU) v = fmaxf(v, 0.f);
        long long off = coff + (long long)(grow0 + i) * ldc + gcol;
        if (Cf) Cf[off] = v;
        if (Cb) Cb[off] = f2bf(v);
      }
    }
  }
}

// ---------------------------------------------------------------------------
// Row softmax over S=2048 bf16 scores, in place (bf16 probs). Each thread
// owns its 8 elements end-to-end — no aliasing across threads.
// ---------------------------------------------------------------------------
__global__ __launch_bounds__(256) void softmax_k(ushort_t* sc, int causal, int crow0) {
  int row = blockIdx.x;
  ushort_t* rp = sc + ((size_t)blockIdx.y * T_ + row) * S_;
  int t = threadIdx.x;
  int valid = causal ? crow0 + row + 1 : S_;
  union { ushort_t u[8]; uint4 v; } in;
  in.v = *(const uint4*)(rp + t * 8);
  float x[8];
#pragma unroll
  for (int j = 0; j < 8; ++j) x[j] = bf2f(in.u[j]);
  float m = -3.0e38f;
#pragma unroll
  for (int j = 0; j < 8; ++j) if (t * 8 + j < valid) m = fmaxf(m, x[j]);
  for (int mk = 1; mk < 64; mk <<= 1) m = fmaxf(m, __shfl_xor(m, mk));
  __shared__ float rbuf[8];
  if ((t & 63) == 0) rbuf[t >> 6] = m;
  __syncthreads();
  m = fmaxf(fmaxf(rbuf[0], rbuf[1]), fmaxf(rbuf[2], rbuf[3]));
  float p[8]; float l = 0.f;
#pragma unroll
  for (int j = 0; j < 8; ++j) { p[j] = (t * 8 + j < valid) ? __expf(x[j] - m) : 0.f; l += p[j]; }
  for (int mk = 1; mk < 64; mk <<= 1) l += __shfl_xor(l, mk);
  if ((t & 63) == 0) rbuf[4 + (t >> 6)] = l;
  __syncthreads();
  l = rbuf[4] + rbuf[5] + rbuf[6] + rbuf[7];
  float inv = 1.f / l;
  union { ushort_t u[8]; uint4 v; } pk;
#pragma unroll
  for (int j = 0; j < 8; ++j) pk.u[j] = f2bf(p[j] * inv);
  *(uint4*)(rp + t * 8) = pk.v;
}

// ---------------------------------------------------------------------------
// out = LN(base + delta) * g + be; writes fp32 (residual) and optional bf16.
// ---------------------------------------------------------------------------
__global__ __launch_bounds__(256) void add_ln_k(
    const float* __restrict__ base, const float* __restrict__ delta,
    const float* __restrict__ g, const float* __restrict__ be,
    float* __restrict__ outf, ushort_t* __restrict__ outb) {
  int row = blockIdx.x * 4 + (threadIdx.x >> 6);
  int lane = threadIdx.x & 63;
  size_t off = (size_t)row * 256 + lane * 4;
  float4 xv = *(const float4*)(base + off);
  float4 dv = *(const float4*)(delta + off);
  float s0 = xv.x + dv.x, s1 = xv.y + dv.y, s2 = xv.z + dv.z, s3 = xv.w + dv.w;
  float sum = s0 + s1 + s2 + s3;
  for (int mk = 1; mk < 64; mk <<= 1) sum += __shfl_xor(sum, mk);
  float mean = sum * (1.f / 256.f);
  float e0 = s0 - mean, e1 = s1 - mean, e2 = s2 - mean, e3 = s3 - mean;
  float ss = e0 * e0 + e1 * e1 + e2 * e2 + e3 * e3;
  for (int mk = 1; mk < 64; mk <<= 1) ss += __shfl_xor(ss, mk);
  float rstd = rsqrtf(ss * (1.f / 256.f) + 1e-5f);
  float4 gv = *(const float4*)(g + lane * 4);
  float4 bv = *(const float4*)(be + lane * 4);
  float o0 = e0 * rstd * gv.x + bv.x, o1 = e1 * rstd * gv.y + bv.y;
  float o2 = e2 * rstd * gv.z + bv.z, o3 = e3 * rstd * gv.w + bv.w;
  float4 ov; ov.x = o0; ov.y = o1; ov.z = o2; ov.w = o3;
  *(float4*)(outf + off) = ov;
  if (outb) {
    union { ushort_t u[4]; uint2 v; } pk;
    pk.u[0] = f2bf(o0); pk.u[1] = f2bf(o1); pk.u[2] = f2bf(o2); pk.u[3] = f2bf(o3);
    *(uint2*)(outb + off) = pk.v;
  }
}

// ---------------------------------------------------------------------------
extern "C" void kernel_launch(void* const* d_in, const int* in_sizes, int n_in,
                              void* d_out, int out_size, void* d_ws, size_t ws_size,
                              hipStream_t stream) {
  const float* y   = (const float*)d_in[0];
  const float* Z   = (const float*)d_in[1];
  const float* Wq1 = (const float*)d_in[3];  const float* bq1 = (const float*)d_in[4];
  const float* Wk1 = (const float*)d_in[5];  const float* bk1 = (const float*)d_in[6];
  const float* Wv1 = (const float*)d_in[7];  const float* bv1 = (const float*)d_in[8];
  const float* Wq2 = (const float*)d_in[9];  const float* bq2 = (const float*)d_in[10];
  const float* Wk2 = (const float*)d_in[11]; const float* bk2 = (const float*)d_in[12];
  const float* Wv2 = (const float*)d_in[13]; const float* bv2 = (const float*)d_in[14];
  const float* W1  = (const float*)d_in[15]; const float* b1  = (const float*)d_in[16];
  const float* W2  = (const float*)d_in[17]; const float* b2  = (const float*)d_in[18];
  const float* g1  = (const float*)d_in[19]; const float* be1 = (const float*)d_in[20];
  const float* g2  = (const float*)d_in[21]; const float* be2 = (const float*)d_in[22];
  const float* g3  = (const float*)d_in[23]; const float* be3 = (const float*)d_in[24];
  float* out = (float*)d_out;

  char* p = (char*)d_ws;
  auto alloc = [&](size_t sz) { char* r = p; p += (sz + 255) & ~(size_t)255; return r; };
  const size_t NBT = (size_t)B_ * T_ * D_;   // 2,097,152 elems
  // Wq1t/Wk1t/Wv1t contiguous (fused QKV weight [768,256]); Wk2t/Wv2t contiguous.
  ushort_t* Wq1t = (ushort_t*)alloc(D_ * D_ * 2);
  ushort_t* Wk1t = (ushort_t*)alloc(D_ * D_ * 2);
  ushort_t* Wv1t = (ushort_t*)alloc(D_ * D_ * 2);
  ushort_t* Wq2t = (ushort_t*)alloc(D_ * D_ * 2);
  ushort_t* Wk2t = (ushort_t*)alloc(D_ * D_ * 2);
  ushort_t* Wv2t = (ushort_t*)alloc(D_ * D_ * 2);
  ushort_t* W1t  = (ushort_t*)alloc((size_t)F_ * D_ * 2);
  ushort_t* W2t  = (ushort_t*)alloc((size_t)D_ * F_ * 2);
  float* bqkv1 = (float*)alloc(768 * 4);
  float* bkv2  = (float*)alloc(512 * 4);
  ushort_t* yb  = (ushort_t*)alloc(NBT * 2);
  ushort_t* Zb  = (ushort_t*)alloc(NBT * 2);
  float*    y1f = (float*)alloc(NBT * 4);
  ushort_t* y1b = (ushort_t*)alloc(NBT * 2);
  float*    y2f = (float*)alloc(NBT * 4);
  ushort_t* y2b = (ushort_t*)alloc(NBT * 2);
  ushort_t* QKVb = (ushort_t*)alloc((size_t)B_ * T_ * 768 * 2);  // [8192,768] interleaved
  ushort_t* Vt   = (ushort_t*)alloc(NBT * 2);                    // [B][D][S]
  ushort_t* Hb = QKVb;   // FFN hidden [8192,1024] aliases QKVb+Vt (16.8MB avail)
  float* tmp = (float*)alloc(NBT * 4);
  ushort_t* sc = (ushort_t*)p;                                   // bf16 scores
  size_t remain = (ws_size > (size_t)(p - (char*)d_ws))
                      ? ws_size - (size_t)(p - (char*)d_ws) : 0;
  const size_t rowb = (size_t)S_ * 2;            // bytes per score row (bf16)
  int CH = 0, TC = 0;
  if (remain >= (size_t)B_ * T_ * rowb)      { CH = B_; TC = T_; }
  else if (remain >= (size_t)T_ * rowb)      { CH = 1;  TC = T_; }
  else {
    int tc = (int)(remain / (rowb * 128)) * 128;
    if (tc > T_) tc = T_;
    CH = 1; TC = tc;
  }

  // --- prep ---
  WP8 wp;
  wp.m[0] = {Wq1, Wq1t, D_, D_}; wp.m[1] = {Wk1, Wk1t, D_, D_};
  wp.m[2] = {Wv1, Wv1t, D_, D_}; wp.m[3] = {Wq2, Wq2t, D_, D_};
  wp.m[4] = {Wk2, Wk2t, D_, D_}; wp.m[5] = {Wv2, Wv2t, D_, D_};
  wp.m[6] = {W1, W1t, D_, F_};   wp.m[7] = {W2, W2t, F_, D_};
  prep_weights_k<<<dim3(16, 16, 8), dim3(64, 4), 0, stream>>>(wp);
  pack_bias_k<<<dim3(5), 256, 0, stream>>>(bq1, bk1, bv1, bk2, bv2, bqkv1, bkv2);
  cvt_k<<<dim3((int)(NBT / 8 / 256), 2), 256, 0, stream>>>(y, yb, Z, Zb);

  auto gemm = [&](const ushort_t* A, int lda, long long sAz,
                  const ushort_t* Bt, int ldb, long long sBz,
                  const float* bias, float* Cf, ushort_t* Cb, int ldc, long long sCz,
                  int M, int N, int K, float alpha, int causal, int kcausal,
                  bool relu, int Zn, int crow0) {
    dim3 g(N / 64, M / 128, Zn);
    if (relu)
      gemm_bt<true><<<g, 256, 0, stream>>>(A, lda, sAz, Bt, ldb, sBz, bias, Cf, Cb, ldc, sCz, K, alpha, causal, kcausal, crow0);
    else
      gemm_bt<false><<<g, 256, 0, stream>>>(A, lda, sAz, Bt, ldb, sBz, bias, Cf, Cb, ldc, sCz, K, alpha, causal, kcausal, crow0);
  };

  // attention over interleaved QKV buffer: Q at col 0, K at col 256, V at col 512
  auto attention = [&](float* attout, int causal) {
    transpose_bf16_k<<<dim3(S_ / 64, D_ / 64, B_), dim3(64, 4), 0, stream>>>(
        QKVb + 512, (long long)S_ * 768, 768, Vt, (long long)D_ * S_, S_, D_);
    if (TC <= 0) return;
    const ushort_t* Q = QKVb;
    const ushort_t* Kc = QKVb + 256;
    for (int b0 = 0; b0 < B_; b0 += CH) {
      for (int t0 = 0; t0 < T_; t0 += TC) {
        int rows = (t0 + TC <= T_) ? TC : (T_ - t0);
        gemm(Q + ((size_t)b0 * T_ + t0) * 768, 768, (long long)T_ * 768,
             Kc + (size_t)b0 * S_ * 768, 768, (long long)S_ * 768,
             nullptr, nullptr, sc, S_, (long long)T_ * S_,
             rows, S_, D_, 0.0625f, causal, 0, false, CH, t0);
        softmax_k<<<dim3(rows, CH), 256, 0, stream>>>(sc, causal, t0);
        gemm(sc, S_, (long long)T_ * S_,
             Vt + (size_t)b0 * D_ * S_, S_, (long long)D_ * S_,
             nullptr, attout + ((size_t)b0 * T_ + t0) * D_, nullptr, D_, (long long)T_ * D_,
             rows, D_, S_, 1.f, 0, causal, false, CH, t0);
      }
    }
  };

  // --- self-attention ---
  gemm(yb, D_, 0, Wq1t, D_, 0, bqkv1, nullptr, QKVb, 768, 0,
       B_ * T_, 768, D_, 1.f, 0, 0, false, 1, 0);
  attention(tmp, 1);
  add_ln_k<<<dim3(B_ * T_ / 4), 256, 0, stream>>>(y, tmp, g1, be1, y1f, y1b);

  // --- cross-attention ---
  gemm(y1b, D_, 0, Wq2t, D_, 0, bq2, nullptr, QKVb, 768, 0,
       B_ * T_, D_, D_, 1.f, 0, 0, false, 1, 0);
  gemm(Zb, D_, 0, Wk2t, D_, 0, bkv2, nullptr, QKVb + 256, 768, 0,
       B_ * S_, 512, D_, 1.f, 0, 0, false, 1, 0);
  attention(tmp, 0);
  add_ln_k<<<dim3(B_ * T_ / 4), 256, 0, stream>>>(y1f, tmp, g2, be2, y2f, y2b);

  // --- FFN ---
  gemm(y2b, D_, 0, W1t, D_, 0, b1, nullptr, Hb, F_, 0,
       B_ * T_, F_, D_, 1.f, 0, 0, true, 1, 0);
  gemm(Hb, F_, 0, W2t, F_, 0, b2, tmp, nullptr, D_, 0,
       B_ * T_, D_, F_, 1.f, 0, 0, false, 1, 0);
  add_ln_k<<<dim3(B_ * T_ / 4), 256, 0, stream>>>(y2f, tmp, g3, be3, out, nullptr);
}